// Round 12
// baseline (123.619 us; speedup 1.0000x reference)
//
#include <hip/hip_runtime.h>
#include <math.h>

// RoI max pooling (JAX reference): features [1,C,H,W] fp32, rois [R,4] int32
// (x1,y1,x2,y2 inclusive), P=7. Boundaries b[i]=trunc(x1 + fl32(rw/7)*i),
// each op rounded separately (no FMA). Setup guarantees 8 <= rw,rh <= 64.
//
// R12: per-wave MLP was ~1-2 (21K cy/wave for 46 loads: VGPR-allocator
// serialized every "ILP" structure; VGPR stuck at 44). Fix by construction:
// global_load_lds row-ring. Each ROI row = one DMA instr (64 lanes x 16B =
// 4 ch x 64 cols -> 1KB ring slot, no dest VGPRs). Issue row i+13, wait
// vmcnt(12), consume row i+1 via ds_read_b128 (1-ahead pipelined) -> 13
// loads in flight always. Bin finalize = colmax write + vectorized
// select-before-max col reduce into LDS res; one batched global write.
// Fixed instr counts (clamped dup issues) keep vmcnt discipline exact;
// tail-cols pass runs BEFORE the ring behind a vmcnt(0) fence.

#define POOL_P 7

typedef __attribute__((address_space(1))) const void gld_src_t;
typedef __attribute__((address_space(3))) void gld_dst_t;

__device__ __forceinline__ float4 max4(float4 a, float4 b) {
  return make_float4(fmaxf(a.x, b.x), fmaxf(a.y, b.y),
                     fmaxf(a.z, b.z), fmaxf(a.w, b.w));
}

__global__ __launch_bounds__(64, 4) void roipool_kernel(
    const float* __restrict__ feat, const int* __restrict__ rois,
    float* __restrict__ out, int C, int H, int W, int R) {
  // XCD-aware decode (verified R5): bid%8 = XCD; XCD x runs channel-group
  // {x, x+8, ...} over all R rois x 2 halves before its next group.
  const int x  = blockIdx.x & 7;
  const int s  = blockIdx.x >> 3;
  const int pass = s / (2 * R);
  const int t    = s - pass * 2 * R;
  const int r    = t >> 1;
  const int half = t & 1;
  const int cg8  = (pass << 3) | x;

  const int lane = threadIdx.x;            // one wave per block
  const int k  = lane >> 4;                // channel within wave (0..3)
  const int li = lane & 15;                // float4 slot in 64-col window
  const int c0 = (cg8 << 3) + (half << 2); // wave's first channel

  const int4 roi = *reinterpret_cast<const int4*>(rois + 4 * r);
  const int x1 = roi.x, y1 = roi.y;
  const int rw = max(roi.z - x1 + 1, 1);
  const int rh = max(roi.w - y1 + 1, 1);
  const int x2 = x1 + rw - 1;

  // bit-exact fp32 bin math: div, mul, add each rounded; trunc==floor (>=0)
  const float sx = __fdiv_rn((float)rw, (float)POOL_P);
  const float sy = __fdiv_rn((float)rh, (float)POOL_P);
  const float x1f = (float)x1, y1f = (float)y1;

  const int xa = x1 & ~3;              // 16B-aligned window start
  const bool tailc = (x2 >= xa + 64);  // cols xa+64..66 (x2 <= xa+66 <= 334)

  const size_t HW = (size_t)H * W;
  const float* fck = feat + (size_t)(c0 + k) * HW;
  // per-lane global source for ROI row i (absolute row y1+i)
  const float* src0 = fck + (size_t)y1 * W + xa + (li << 2);
  const float* pt   = fck + xa + 64;   // tail cols base

  __shared__ float ring[16][256];      // 16 row slots x 1KB
  __shared__ float colmax[4][80];      // per-bin col maxes (+tail, headroom)
  __shared__ float res[4 * 49];        // [k][ph*7+pw]
  __shared__ float4 tailstg[POOL_P][4];// tail col maxes per (ph, k)

  const float NEG = -__builtin_inff();
  const float4 NEG4 = make_float4(NEG, NEG, NEG, NEG);

  // total ROI rows T = b[7] - y1 (bins partition [y1, b7))
  const int b7 = (int)__fadd_rn(y1f, __fmul_rn(sy, (float)POOL_P));
  const int T  = b7 - y1;              // 7..64

  // ---- rare tail-cols pass (~4% of ROIs), fully drained before the ring ----
  if (tailc && li == 0) {
    int hprev = y1;
#pragma unroll
    for (int ph = 0; ph < POOL_P; ++ph) {
      const int hend = (int)__fadd_rn(y1f, __fmul_rn(sy, (float)(ph + 1)));
      float4 tm = NEG4;
      for (int h = hprev; h < hend; ++h)
        tm = max4(tm, *reinterpret_cast<const float4*>(pt + (size_t)h * W));
      hprev = hend;
      tailstg[ph][k] = tm;
    }
  }
  // fence: no stray VGPR loads outstanding -> ring vmcnt counts are exact
  asm volatile("s_waitcnt vmcnt(0)" ::: "memory");

  // ---- prologue: issue rows 0..12 into ring slots 0..12 ----
#pragma unroll
  for (int j = 0; j < 13; ++j) {
    const int rr = min(j, T - 1);
    __builtin_amdgcn_global_load_lds((gld_src_t*)(src0 + (size_t)rr * W),
                                     (gld_dst_t*)&ring[j][0], 16, 0, 0);
  }

  // first row: wait (13 outstanding -> 12 leaves row 0 retired), read v0
  asm volatile("s_waitcnt vmcnt(12)" ::: "memory");
  float4 v = *reinterpret_cast<const float4*>(&ring[0][lane << 2]);

  // ---- main ring loop: row i consumed, row i+13 issued, row i+1 read ----
  int ph = 0;
  int eoff = (int)__fadd_rn(y1f, __fmul_rn(sy, 1.0f)) - y1;  // end of bin 0
  float4 m = NEG4;
  const size_t ob = ((size_t)r * C + c0) * (POOL_P * POOL_P);

  for (int i = 0; i < T; ++i) {
    // issue row i+13 (clamped dup near the end; lands in slot of row i-3,
    // whose ds_read was consumed 3 iterations ago)
    const int nr = min(i + 13, T - 1);
    __builtin_amdgcn_global_load_lds((gld_src_t*)(src0 + (size_t)nr * W),
                                     (gld_dst_t*)&ring[(i + 13) & 15][0],
                                     16, 0, 0);
    // row i+1 retired: issued = i+14, need outstanding <= 12
    asm volatile("s_waitcnt vmcnt(12)" ::: "memory");
    const float4 vn =
        *reinterpret_cast<const float4*>(&ring[(i + 1) & 15][lane << 2]);
    m = max4(m, v);                    // consume row i (loaded last iter)
    v = vn;

    if (i + 1 == eoff) {               // ---- bin ph finalize (uniform) ----
      *reinterpret_cast<float4*>(&colmax[k][li << 2]) = m;
      if (tailc && li == 0)
        *reinterpret_cast<float4*>(&colmax[k][64]) = tailstg[ph][k];
      // vectorized col reduce: 28 lanes, select-before-max (stale-safe)
      if (lane < 4 * POOL_P) {
        const int rk  = lane / POOL_P;
        const int rpw = lane - rk * POOL_P;
        const int w0 = (int)__fadd_rn(x1f, __fmul_rn(sx, (float)rpw)) - xa;
        const int w1 = (int)__fadd_rn(x1f, __fmul_rn(sx, (float)(rpw + 1))) - xa;
        const int a0 = w0 & ~3;        // w1 - a0 <= 16
        const float* sq = &colmax[rk][a0];
        float4 t0 = *reinterpret_cast<const float4*>(sq);
        float4 t1 = *reinterpret_cast<const float4*>(sq + 4);
        float4 t2 = *reinterpret_cast<const float4*>(sq + 8);
        float4 t3 = *reinterpret_cast<const float4*>(sq + 12);
        const int lo = w0 - a0, hi = w1 - a0;
        float e[16] = {t0.x, t0.y, t0.z, t0.w, t1.x, t1.y, t1.z, t1.w,
                       t2.x, t2.y, t2.z, t2.w, t3.x, t3.y, t3.z, t3.w};
        float mm = NEG;
#pragma unroll
        for (int jj = 0; jj < 16; ++jj) {
          const float vv = (jj >= lo && jj < hi) ? e[jj] : NEG;
          mm = fmaxf(mm, vv);
        }
        res[rk * 49 + ph * POOL_P + rpw] = mm;
      }
      ++ph;
      eoff = (int)__fadd_rn(y1f, __fmul_rn(sy, (float)(ph + 1))) - y1;
      m = NEG4;
    }
  }

  // ---- batched coalesced output: 196 contiguous floats ----
#pragma unroll
  for (int i2 = lane; i2 < 4 * POOL_P * POOL_P; i2 += 64) {
    out[ob + i2] = res[i2];
  }
}

extern "C" void kernel_launch(void* const* d_in, const int* in_sizes, int n_in,
                              void* d_out, int out_size, void* d_ws, size_t ws_size,
                              hipStream_t stream) {
  const float* feat = (const float*)d_in[0];
  const int*   rois = (const int*)d_in[1];
  float*       out  = (float*)d_out;

  const int C = 256, H = 336, W = 336;  // fixed by setup_inputs()
  const int R = in_sizes[1] / 4;        // 256 rois

  const int n_cg8 = C / 8;              // 32 channel groups
  dim3 grid(n_cg8 * R * 2), block(64);  // 1 wave/block, 2 halves per group
  roipool_kernel<<<grid, block, 0, stream>>>(feat, rois, out, C, H, W, R);
}

// Round 13
// 58.599 us; speedup vs baseline: 2.1096x; 2.1096x over previous
//
#include <hip/hip_runtime.h>
#include <math.h>

// RoI max pooling (JAX reference): features [1,C,H,W] fp32, rois [R,4] int32
// (x1,y1,x2,y2 inclusive), P=7. Boundaries b[i]=trunc(x1 + fl32(rw/7)*i),
// each op rounded separately (no FMA). Setup guarantees 8 <= rw,rh <= 64.
//
// R13: decisive MLP test. R10-R12 nulls left two candidates: L3->L2 supply
// ceiling (~2.9 TB/s observed across all structures) vs per-wave MLP ~2
// (allocator serializes dest-VGPR loads; VGPR stuck at 44). Force MLP by
// lane geometry: 256-thr blocks, lane = jj(row)x k(ch)x s(slot), wave w owns
// slots 4w..4w+3. Per bin per wave: 1-3 load instrs (4 rows in lanes,
// clamped dups), 7 bins independent -> ~11 independent loads/wave with ~3
// float4 live. Cross-jj reduce = 2 shfl_xor (partners share sl -> exec-mask
// safe). One barrier, then R11's vectorized select-before-max col reduce.
// XCD pass decode (R5) and slot clamp (R7) preserved.

#define POOL_P 7

__device__ __forceinline__ float4 max4(float4 a, float4 b) {
  return make_float4(fmaxf(a.x, b.x), fmaxf(a.y, b.y),
                     fmaxf(a.z, b.z), fmaxf(a.w, b.w));
}

__device__ __forceinline__ float4 shflx4(float4 v, int mask) {
  return make_float4(__shfl_xor(v.x, mask, 64), __shfl_xor(v.y, mask, 64),
                     __shfl_xor(v.z, mask, 64), __shfl_xor(v.w, mask, 64));
}

__global__ __launch_bounds__(256, 4) void roipool_kernel(
    const float* __restrict__ feat, const int* __restrict__ rois,
    float* __restrict__ out, int C, int H, int W, int R) {
  // XCD-aware decode (verified R5): bid%8 = XCD; XCD x runs channel-group
  // {x, x+8, ...} over all R rois x 2 halves before its next group.
  const int x  = blockIdx.x & 7;
  const int s_ = blockIdx.x >> 3;
  const int pass = s_ / (2 * R);
  const int t    = s_ - pass * 2 * R;
  const int r    = t >> 1;
  const int half = t & 1;
  const int cg8  = (pass << 3) | x;

  const int tid  = threadIdx.x;
  const int lane = tid & 63;
  const int w    = tid >> 6;               // wave 0..3
  const int jj   = lane >> 4;              // row sublane 0..3
  const int k    = (lane >> 2) & 3;        // channel 0..3
  const int sl   = (w << 2) | (lane & 3);  // float4 slot 0..15
  const int c0 = (cg8 << 3) + (half << 2); // block's first channel

  const int4 roi = *reinterpret_cast<const int4*>(rois + 4 * r);
  const int x1 = roi.x, y1 = roi.y;
  const int rw = max(roi.z - x1 + 1, 1);
  const int rh = max(roi.w - y1 + 1, 1);
  const int x2 = x1 + rw - 1;

  // bit-exact fp32 bin math: div, mul, add each rounded; trunc==floor (>=0)
  const float sx = __fdiv_rn((float)rw, (float)POOL_P);
  const float sy = __fdiv_rn((float)rh, (float)POOL_P);
  const float x1f = (float)x1, y1f = (float)y1;

  const int xa = x1 & ~3;              // 16B-aligned window start
  const bool tailc = (x2 >= xa + 64);  // cols xa+64..66 (x2 <= xa+66 <= 334)
  const int lslot = min((x2 - xa) >> 2, 15);  // last needed slot in 0..15

  const size_t HW = (size_t)H * W;
  const int W4 = W >> 2;               // 84 float4 per row
  const float* fck = feat + (size_t)(c0 + k) * HW;
  const float4* pmb = reinterpret_cast<const float4*>(fck + xa) + sl;

  __shared__ float stg[4][POOL_P][80]; // [k][ph][col]

  const float NEG = -__builtin_inff();
  const float4 NEG4 = make_float4(NEG, NEG, NEG, NEG);

  // ---- phase 1: per bin, rows 4-at-a-time in lanes; 7 bins independent ----
  if (sl <= lslot) {                   // one divergence mask; partners share sl
    int hprev = y1;                    // b[0] = trunc(y1f) = y1 exactly
#pragma unroll
    for (int ph = 0; ph < POOL_P; ++ph) {
      const int hend = (int)__fadd_rn(y1f, __fmul_rn(sy, (float)(ph + 1)));
      const int cnt = hend - hprev;    // 1..10 (rh <= 64), wave-uniform
      const int e = cnt - 1;
      const float4* q = pmb + (size_t)hprev * W4;
      hprev = hend;
      float4 m = q[(size_t)min(jj, e) * W4];
      if (cnt > 4) m = max4(m, q[(size_t)min(jj + 4, e) * W4]);
      if (cnt > 8) m = max4(m, q[(size_t)min(jj + 8, e) * W4]);
      // reduce across jj (bits 4,5 of lane); dups idempotent under max
      m = max4(m, shflx4(m, 16));
      m = max4(m, shflx4(m, 32));
      if (jj == 0)
        *reinterpret_cast<float4*>(&stg[k][ph][sl << 2]) = m;
    }
  }

  // ---- rare tail pass (~4% of ROIs): cols xa+64..xa+66, threads 0..3 ----
  if (tailc && tid < 4) {
    const float* ptk = feat + (size_t)(c0 + tid) * HW + xa + 64;
    int hprev = y1;
#pragma unroll
    for (int ph = 0; ph < POOL_P; ++ph) {
      const int hend = (int)__fadd_rn(y1f, __fmul_rn(sy, (float)(ph + 1)));
      float4 tm = NEG4;
      for (int h = hprev; h < hend; ++h)
        tm = max4(tm, *reinterpret_cast<const float4*>(ptk + (size_t)h * W));
      hprev = hend;
      *reinterpret_cast<float4*>(&stg[tid][ph][64]) = tm;
    }
  }

  __syncthreads();

  // ---- phase 2: 196 threads do the vectorized column-bin reduce ----
  if (tid < 4 * POOL_P * POOL_P) {
    const int k2 = tid / (POOL_P * POOL_P);
    const int j  = tid - k2 * (POOL_P * POOL_P);
    const int ph = j / POOL_P;
    const int pw = j - ph * POOL_P;
    // bin edges recomputed inline (bit-exact; no runtime-indexed array)
    const int w0 = (int)__fadd_rn(x1f, __fmul_rn(sx, (float)pw)) - xa;
    const int w1 = (int)__fadd_rn(x1f, __fmul_rn(sx, (float)(pw + 1))) - xa;
    const int a0 = w0 & ~3;            // w1 - a0 <= 13 < 16
    const float* sq = &stg[k2][ph][a0];
    float4 t0 = *reinterpret_cast<const float4*>(sq);
    float4 t1 = *reinterpret_cast<const float4*>(sq + 4);
    float4 t2 = *reinterpret_cast<const float4*>(sq + 8);
    float4 t3 = *reinterpret_cast<const float4*>(sq + 12);
    const int lo = w0 - a0, hi = w1 - a0;
    float e[16] = {t0.x, t0.y, t0.z, t0.w, t1.x, t1.y, t1.z, t1.w,
                   t2.x, t2.y, t2.z, t2.w, t3.x, t3.y, t3.z, t3.w};
    float m = NEG;
#pragma unroll
    for (int jx = 0; jx < 16; ++jx) {  // select-before-max: stale-slot safe
      const float v = (jx >= lo && jx < hi) ? e[jx] : NEG;
      m = fmaxf(m, v);
    }
    const size_t ob = ((size_t)r * C + c0) * (POOL_P * POOL_P);
    out[ob + tid] = m;                 // contiguous 196 floats
  }
}

extern "C" void kernel_launch(void* const* d_in, const int* in_sizes, int n_in,
                              void* d_out, int out_size, void* d_ws, size_t ws_size,
                              hipStream_t stream) {
  const float* feat = (const float*)d_in[0];
  const int*   rois = (const int*)d_in[1];
  float*       out  = (float*)d_out;

  const int C = 256, H = 336, W = 336;  // fixed by setup_inputs()
  const int R = in_sizes[1] / 4;        // 256 rois

  const int n_cg8 = C / 8;              // 32 channel groups
  dim3 grid(n_cg8 * R * 2), block(256); // 4 waves/block, slots partitioned
  roipool_kernel<<<grid, block, 0, stream>>>(feat, rois, out, C, H, W, R);
}

// Round 14
// 54.072 us; speedup vs baseline: 2.2862x; 1.0837x over previous
//
#include <hip/hip_runtime.h>
#include <math.h>

// RoI max pooling (JAX reference): features [1,C,H,W] fp32, rois [R,4] int32
// (x1,y1,x2,y2 inclusive), P=7. Boundaries b[i]=trunc(x1 + fl32(rw/7)*i),
// each op rounded separately (no FMA). Setup guarantees 8 <= rw,rh <= 64.
//
// R14: byte-diet discriminator. R2/R11/R13 all saturate at ~8.5 TB/s
// effective vector-load byte service (~33 B/cy/CU) across totally different
// structures -> byte-stream bound on the L1 path. This round removes the
// last avoidable lane-bytes: exact row counts per bin (no clamp-dup loads;
// E[rows] 6.2 -> 5.07), unroll-2 for modest MLP. If this lands ~43us the
// lane-byte-return model is right; if flat ~51us we are at the line-fill
// floor and done. Everything else = R11 (XCD pass decode, slot clamp + exec
// mask, stg[4][7][80], vectorized select-before-max phase 2).

#define POOL_P 7

__device__ __forceinline__ float4 max4(float4 a, float4 b) {
  return make_float4(fmaxf(a.x, b.x), fmaxf(a.y, b.y),
                     fmaxf(a.z, b.z), fmaxf(a.w, b.w));
}

__global__ __launch_bounds__(64, 4) void roipool_kernel(
    const float* __restrict__ feat, const int* __restrict__ rois,
    float* __restrict__ out, int C, int H, int W, int R) {
  // XCD-aware decode (verified R5): bid%8 = XCD; XCD x runs channel-group
  // {x, x+8, ...} over all R rois x 2 halves before its next group.
  const int x  = blockIdx.x & 7;
  const int s  = blockIdx.x >> 3;
  const int pass = s / (2 * R);
  const int t    = s - pass * 2 * R;
  const int r    = t >> 1;
  const int half = t & 1;
  const int cg8  = (pass << 3) | x;        // 8-channel group

  const int lane = threadIdx.x;            // one wave per block
  const int k  = lane >> 4;                // channel within wave (0..3)
  const int li = lane & 15;                // float4 slot in 64-col window
  const int c0 = (cg8 << 3) + (half << 2); // wave's first channel

  const int4 roi = *reinterpret_cast<const int4*>(rois + 4 * r);
  const int x1 = roi.x, y1 = roi.y;
  const int rw = max(roi.z - x1 + 1, 1);
  const int rh = max(roi.w - y1 + 1, 1);
  const int x2 = x1 + rw - 1;

  // bit-exact fp32 bin math: div, mul, add each rounded; trunc==floor (>=0)
  const float sx = __fdiv_rn((float)rw, (float)POOL_P);
  const float sy = __fdiv_rn((float)rh, (float)POOL_P);
  const float x1f = (float)x1, y1f = (float)y1;

  const int xa = x1 & ~3;              // 16B-aligned window start
  const bool tailc = (x2 >= xa + 64);  // cols xa+64..66 (x2 <= xa+66 <= 334)
  const int lslot = min((x2 - xa) >> 2, 15);  // last needed float4 slot

  const size_t HW = (size_t)H * W;
  const int W4 = W >> 2;               // 84 float4 per row
  const float* fck = feat + (size_t)(c0 + k) * HW;
  const float4* pmb = reinterpret_cast<const float4*>(fck + xa) + li;
  const float* pt  = fck + xa + 64;

  __shared__ float stg[4][POOL_P][80]; // [k][ph][col]; 80: vec-read headroom

  const float NEG = -__builtin_inff();

  // ---- phase 1: masked lanes, EXACT row counts (zero dup loads) ----
  if (li <= lslot) {                   // one divergence mask for all loads
    int hprev = y1;                    // b[0] = trunc(y1f) = y1 exactly
#pragma unroll
    for (int ph = 0; ph < POOL_P; ++ph) {
      const int hend = (int)__fadd_rn(y1f, __fmul_rn(sy, (float)(ph + 1)));
      const int cnt = hend - hprev;    // 1..10 (rh <= 64), wave-uniform
      const float4* q = pmb + (size_t)hprev * W4;
      hprev = hend;
      float4 m = q[0];                 // row 0 always exists
      int h = 1;
      for (; h + 1 < cnt; h += 2) {    // unroll-2: 2 loads in flight
        float4 a = q[(size_t)h * W4];
        float4 b = q[(size_t)h * W4 + W4];
        m = max4(m, max4(a, b));
      }
      if (h < cnt)                     // even-cnt remainder
        m = max4(m, q[(size_t)h * W4]);
      *reinterpret_cast<float4*>(&stg[k][ph][li << 2]) = m;
    }
  }

  // ---- rare tail pass (~4% of ROIs): cols xa+64..xa+66 ----
  if (tailc && li == 0) {
    int hprev = y1;
#pragma unroll
    for (int ph = 0; ph < POOL_P; ++ph) {
      const int hend = (int)__fadd_rn(y1f, __fmul_rn(sy, (float)(ph + 1)));
      float4 tm = make_float4(NEG, NEG, NEG, NEG);
      for (int h = hprev; h < hend; ++h)
        tm = max4(tm, *reinterpret_cast<const float4*>(pt + (size_t)h * W));
      hprev = hend;
      *reinterpret_cast<float4*>(&stg[k][ph][64]) = tm;
    }
  }

  // ---- phase 2: vectorized column-bin reduce, write out directly ----
  // wave-private LDS: program order + lgkmcnt ordering, no barrier needed
  const size_t ob = ((size_t)r * C + c0) * (POOL_P * POOL_P);
#pragma unroll
  for (int i = lane; i < 4 * POOL_P * POOL_P; i += 64) {
    const int k2 = i / (POOL_P * POOL_P);
    const int j  = i - k2 * (POOL_P * POOL_P);
    const int ph = j / POOL_P;
    const int pw = j - ph * POOL_P;
    // bin edges recomputed inline (bit-exact; no runtime-indexed array)
    const int w0 = (int)__fadd_rn(x1f, __fmul_rn(sx, (float)pw)) - xa;
    const int w1 = (int)__fadd_rn(x1f, __fmul_rn(sx, (float)(pw + 1))) - xa;
    const int a0 = w0 & ~3;              // 16B-aligned; w1-a0 <= 13 < 16
    const float* sq = &stg[k2][ph][a0];
    float4 t0 = *reinterpret_cast<const float4*>(sq);
    float4 t1 = *reinterpret_cast<const float4*>(sq + 4);
    float4 t2 = *reinterpret_cast<const float4*>(sq + 8);
    float4 t3 = *reinterpret_cast<const float4*>(sq + 12);
    const int lo = w0 - a0, hi = w1 - a0;
    float e[16] = {t0.x, t0.y, t0.z, t0.w, t1.x, t1.y, t1.z, t1.w,
                   t2.x, t2.y, t2.z, t2.w, t3.x, t3.y, t3.z, t3.w};
    float m = NEG;
#pragma unroll
    for (int jj = 0; jj < 16; ++jj) {    // select-before-max: stale-slot safe
      const float v = (jj >= lo && jj < hi) ? e[jj] : NEG;
      m = fmaxf(m, v);
    }
    out[ob + i] = m;                     // contiguous across lanes
  }
}

extern "C" void kernel_launch(void* const* d_in, const int* in_sizes, int n_in,
                              void* d_out, int out_size, void* d_ws, size_t ws_size,
                              hipStream_t stream) {
  const float* feat = (const float*)d_in[0];
  const int*   rois = (const int*)d_in[1];
  float*       out  = (float*)d_out;

  const int C = 256, H = 336, W = 336;  // fixed by setup_inputs()
  const int R = in_sizes[1] / 4;        // 256 rois

  const int n_cg8 = C / 8;              // 32 channel groups
  dim3 grid(n_cg8 * R * 2), block(64);  // 1 wave/block, 2 halves per group
  roipool_kernel<<<grid, block, 0, stream>>>(feat, rois, out, C, H, W, R);
}

// Round 15
// 51.114 us; speedup vs baseline: 2.4185x; 1.0579x over previous
//
#include <hip/hip_runtime.h>
#include <math.h>

// RoI max pooling (JAX reference): features [1,C,H,W] fp32, rois [R,4] int32
// (x1,y1,x2,y2 inclusive), P=7. Boundaries b[i]=trunc(x1 + fl32(rw/7)*i),
// each op rounded separately (no FMA). Setup guarantees 8 <= rw,rh <= 64.
//
// R15 = R11 verbatim (best measured: 51.0 us). R12(DMA ring)/R13(forced
// MLP)/R14(byte diet) all confirmed the floor is the L1/TA line-service
// path: ~500 MB compulsory line fills at ~33-40 B/cy/CU => ~50 us. Final.
//
// Structure: XCD pass decode (R5: FETCH 285->65MB), 1-wave blocks (R8),
// straight-line clamped loads w/ row-count dispatch + exec-masked dup lanes
// (R10/R11), wave-private LDS staging [k][ph][80], vectorized
// select-before-max column reduce, contiguous 196-float writes.

#define POOL_P 7

__device__ __forceinline__ float4 max4(float4 a, float4 b) {
  return make_float4(fmaxf(a.x, b.x), fmaxf(a.y, b.y),
                     fmaxf(a.z, b.z), fmaxf(a.w, b.w));
}

__global__ __launch_bounds__(64, 4) void roipool_kernel(
    const float* __restrict__ feat, const int* __restrict__ rois,
    float* __restrict__ out, int C, int H, int W, int R) {
  // XCD-aware decode: bid%8 = XCD; XCD x runs channel-group {x, x+8, ...}
  // over all R rois x 2 halves (one "pass") before its next group.
  const int x  = blockIdx.x & 7;
  const int s  = blockIdx.x >> 3;
  const int pass = s / (2 * R);
  const int t    = s - pass * 2 * R;
  const int r    = t >> 1;
  const int half = t & 1;
  const int cg8  = (pass << 3) | x;        // 8-channel group

  const int lane = threadIdx.x;            // one wave per block
  const int k  = lane >> 4;                // channel within wave (0..3)
  const int li = lane & 15;                // float4 slot in 64-col window
  const int c0 = (cg8 << 3) + (half << 2); // wave's first channel

  const int4 roi = *reinterpret_cast<const int4*>(rois + 4 * r);
  const int x1 = roi.x, y1 = roi.y;
  const int rw = max(roi.z - x1 + 1, 1);
  const int rh = max(roi.w - y1 + 1, 1);
  const int x2 = x1 + rw - 1;

  // bit-exact fp32 bin math: div, mul, add each rounded; trunc==floor (>=0)
  const float sx = __fdiv_rn((float)rw, (float)POOL_P);
  const float sy = __fdiv_rn((float)rh, (float)POOL_P);
  const float x1f = (float)x1, y1f = (float)y1;

  const int xa = x1 & ~3;              // 16B-aligned window start
  const bool tailc = (x2 >= xa + 64);  // cols xa+64..66 (x2 <= xa+66 <= 334)
  const int lslot = min((x2 - xa) >> 2, 15);  // last needed float4 slot

  const size_t HW = (size_t)H * W;
  const int W4 = W >> 2;               // 84 float4 per row
  const float* fck = feat + (size_t)(c0 + k) * HW;
  const float4* pmb = reinterpret_cast<const float4*>(fck + xa) + li;
  const float* pt  = fck + xa + 64;

  __shared__ float stg[4][POOL_P][80]; // [k][ph][col]; 80: vec-read headroom

  const float NEG = -__builtin_inff();

  // ---- phase 1: masked lanes, row-count-dispatched clamped loads ----
  if (li <= lslot) {                   // one divergence mask for all loads
    int hprev = y1;                    // b[0] = trunc(y1f) = y1 exactly
#pragma unroll
    for (int ph = 0; ph < POOL_P; ++ph) {
      const int hend = (int)__fadd_rn(y1f, __fmul_rn(sy, (float)(ph + 1)));
      const int cnt = hend - hprev;    // 1..10 (rh <= 64)
      const int e84 = (cnt - 1) * 84;  // wave-uniform row clamp (float4 units)
      const float4* q = pmb + (size_t)hprev * W4;
      hprev = hend;
      float4 m = q[0];
      m = max4(m, q[min(84,  e84)]);   // dups when cnt<4: same lines, L1 hits
      m = max4(m, q[min(168, e84)]);
      m = max4(m, q[min(252, e84)]);
      if (cnt > 4) {
        float4 a = q[336];             // cnt>=5 => e84>=336: unclamped
        float4 b = q[min(420, e84)];
        float4 c = q[min(504, e84)];
        float4 d = q[min(588, e84)];
        m = max4(m, max4(max4(a, b), max4(c, d)));
      }
      if (cnt > 8) {                   // rare: rh >= 57
        const float4* qq = q + 672;
        for (int h = 8; h < cnt; ++h) { m = max4(m, qq[0]); qq += 84; }
      }
      *reinterpret_cast<float4*>(&stg[k][ph][li << 2]) = m;
    }
  }

  // ---- rare tail pass (~4% of ROIs): cols xa+64..xa+66 ----
  if (tailc && li == 0) {
    int hprev = y1;
#pragma unroll
    for (int ph = 0; ph < POOL_P; ++ph) {
      const int hend = (int)__fadd_rn(y1f, __fmul_rn(sy, (float)(ph + 1)));
      float4 tm = make_float4(NEG, NEG, NEG, NEG);
      for (int h = hprev; h < hend; ++h)
        tm = max4(tm, *reinterpret_cast<const float4*>(pt + (size_t)h * W));
      hprev = hend;
      *reinterpret_cast<float4*>(&stg[k][ph][64]) = tm;
    }
  }

  // ---- phase 2: vectorized column-bin reduce, write out directly ----
  // wave-private LDS: program order + lgkmcnt ordering, no barrier needed
  const size_t ob = ((size_t)r * C + c0) * (POOL_P * POOL_P);
#pragma unroll
  for (int i = lane; i < 4 * POOL_P * POOL_P; i += 64) {
    const int k2 = i / (POOL_P * POOL_P);
    const int j  = i - k2 * (POOL_P * POOL_P);
    const int ph = j / POOL_P;
    const int pw = j - ph * POOL_P;
    // bin edges recomputed inline (bit-exact; no runtime-indexed array)
    const int w0 = (int)__fadd_rn(x1f, __fmul_rn(sx, (float)pw)) - xa;
    const int w1 = (int)__fadd_rn(x1f, __fmul_rn(sx, (float)(pw + 1))) - xa;
    const int a0 = w0 & ~3;              // 16B-aligned; w1-a0 <= 13 < 16
    const float* sq = &stg[k2][ph][a0];
    float4 t0 = *reinterpret_cast<const float4*>(sq);
    float4 t1 = *reinterpret_cast<const float4*>(sq + 4);
    float4 t2 = *reinterpret_cast<const float4*>(sq + 8);
    float4 t3 = *reinterpret_cast<const float4*>(sq + 12);
    const int lo = w0 - a0, hi = w1 - a0;
    float e[16] = {t0.x, t0.y, t0.z, t0.w, t1.x, t1.y, t1.z, t1.w,
                   t2.x, t2.y, t2.z, t2.w, t3.x, t3.y, t3.z, t3.w};
    float m = NEG;
#pragma unroll
    for (int jj = 0; jj < 16; ++jj) {    // select-before-max: stale-slot safe
      const float v = (jj >= lo && jj < hi) ? e[jj] : NEG;
      m = fmaxf(m, v);
    }
    out[ob + i] = m;                     // contiguous across lanes
  }
}

extern "C" void kernel_launch(void* const* d_in, const int* in_sizes, int n_in,
                              void* d_out, int out_size, void* d_ws, size_t ws_size,
                              hipStream_t stream) {
  const float* feat = (const float*)d_in[0];
  const int*   rois = (const int*)d_in[1];
  float*       out  = (float*)d_out;

  const int C = 256, H = 336, W = 336;  // fixed by setup_inputs()
  const int R = in_sizes[1] / 4;        // 256 rois

  const int n_cg8 = C / 8;              // 32 channel groups
  dim3 grid(n_cg8 * R * 2), block(64);  // 1 wave/block, 2 halves per group
  roipool_kernel<<<grid, block, 0, stream>>>(feat, rois, out, C, H, W, R);
}